// Round 4
// baseline (216.972 us; speedup 1.0000x reference)
//
#include <hip/hip_runtime.h>

#define BB 256
#define NN 4096
#define CC 16
#define WW 10
#define LL 4087  // N - W + 1
#define EPSF 1e-5f

// global -> LDS direct copy, 16 B per lane, dest = wave-uniform base (+ lane*16 by HW)
#define GLOAD16(gsrc, ldst)                                                                  \
    __builtin_amdgcn_global_load_lds((const __attribute__((address_space(1))) void*)(gsrc),  \
                                     (__attribute__((address_space(3))) void*)(ldst), 16, 0, 0)

// ---------------- Kernel 0: pack + zero-pad weights into ws (512 KB) ----------------
// pk[n*16+c] = {Wr[c,n], Wi[c,n]}, zeros for n >= LL
__global__ __launch_bounds__(256) void pack_weights(const float* __restrict__ Wr,
                                                    const float* __restrict__ Wi,
                                                    float2* __restrict__ pk) {
    int tg = blockIdx.x * 256 + threadIdx.x;  // [0, 65536)
    int n = tg >> 4, c = tg & 15;
    float2 v = make_float2(0.f, 0.f);
    if (n < LL) { v.x = Wr[c * LL + n]; v.y = Wi[c * LL + n]; }
    pk[tg] = v;
}

// ---------------- Kernel 1 (R9): counted-vmcnt pipelined LDS staging ----------------
// HISTORY:
//  R3: float4/nt loads regressed. R5: BN fusion regressed.
//  R6 FAILED: reg batching under 64-VGPR cap -> scratch spill (319MB writes), 213us.
//  R7 NEUTRAL (~65us): batched reg loads, no spill. R8 NEUTRAL (~66us): LDS staging,
//    __syncthreads per tile. THREE structures all ~65us = 3x the 20us BW floor.
//    Common factor: vmcnt(0) drain every tile/chunk (compiler inserts it before
//    s_barrier) -> pipeline never >1 tile deep, HBM latency exposed 16-32x.
//  R9: T3+T4 pattern (guide m218: counted-vmcnt vs drain-0 = +38-73%). 32 tiles x
//    128 rows, 4 buffers each for x/pk (128 KiB LDS). Every wave issues EXACTLY
//    2 gload_lds per tile (uniform -> countable). Loop: s_waitcnt vmcnt(2) ->
//    raw s_barrier -> issue tile t+2 -> compute tile t. Never vmcnt(0) mid-loop.
//    Halo (w-window) read from previous tile's buffer (branchless addr select);
//    tile0 halo = 9 pre-zeroed rows in buf3 (restaged at t=1 AFTER everyone's
//    tile0 compute -- barrier-ordered, race-free).
__global__ __launch_bounds__(1024, 4) void fused_pipe(const float* __restrict__ x,
                                                      const float2* __restrict__ pk,
                                                      const float* __restrict__ Wnl,
                                                      const float* __restrict__ Wor,
                                                      const float* __restrict__ Woi,
                                                      float* __restrict__ outraw) {
    // smem: [0,65536) x bufs 0..3 (16 KiB each) | [65536,131072) pk bufs 0..3
    // epilogue overlays [0,23040) (x bufs 0/1: last read at tiles 28/29, safe)
    __shared__ __align__(16) char smem[131072];

    const int b = blockIdx.x;
    const int tid = threadIdx.x;
    const int c = tid & 15;
    const int tc = tid >> 4;     // 0..63
    const int base = tc * 2;     // n-offset of this thread's 2-row run within a tile
    const int lane = tid & 63, wave = tid >> 6;

    // per-wave staging source pointers (wave stages rows [w*8, w*8+8) of each tile)
    const char* __restrict__ xsrc =
        (const char*)x + (size_t)b * (NN * CC * 8) + wave * 1024 + lane * 16;
    const char* __restrict__ psrc = (const char*)pk + wave * 1024 + lane * 16;

#define STAGE(u)                                                            \
    do {                                                                    \
        GLOAD16(xsrc + (size_t)(u) * 16384,                                 \
                smem + ((u) & 3) * 16384 + wave * 1024);                    \
        GLOAD16(psrc + (size_t)(u) * 16384,                                 \
                smem + 65536 + ((u) & 3) * 16384 + wave * 1024);            \
    } while (0)

    float fr[WW], fi[WW];
#pragma unroll
    for (int w = 0; w < WW; ++w) { fr[w] = 0.f; fi[w] = 0.f; }

    // ---- prologue: issue tiles 0,1 (4 loads/wave); zero tile0's halo rows ----
    STAGE(0);
    STAGE(1);
    // tile0 halo reads buf3 rows 119..127 -> zero them (288 floats)
    if (tid < 288) ((float*)(smem + 65536 + 3 * 16384 + 119 * 128))[tid] = 0.f;
    asm volatile("s_waitcnt lgkmcnt(0)" ::: "memory");  // drain own ds_writes pre-barrier

#pragma unroll 1
    for (int t = 0; t < 32; ++t) {
        // own tile-t loads done (tile t+1's 2 stay in flight); then collective barrier
        if (t < 31) {
            asm volatile("s_waitcnt vmcnt(2)" ::: "memory");
        } else {
            asm volatile("s_waitcnt vmcnt(0)" ::: "memory");
        }
        __builtin_amdgcn_s_barrier();
        __builtin_amdgcn_sched_barrier(0);  // rule #18: no hoisting past the gate

        // issue tile t+2 -> writes buf (t+2)&3 = (t-2)&3; its last reader (tile
        // t-1 halo) finished before this barrier. Loads span future barriers.
        if (t + 2 < 32) STAGE(t + 2);

        const float2* __restrict__ xb = (const float2*)(smem + (t & 3) * 16384);
        const float2* __restrict__ pc = (const float2*)(smem + 65536 + (t & 3) * 16384);
        const float2* __restrict__ pp = (const float2*)(smem + 65536 + ((t + 3) & 3) * 16384);

        // W window rows t*128 + base + k - 9, k=0..10; r<0 -> prev buffer row 128+r
        float2 wv[11];
#pragma unroll
        for (int k = 0; k < 11; ++k) {
            const int r = base + k - 9;
            const float2* __restrict__ sp =
                (r < 0) ? (pp + ((r + 128) * 16 + c)) : (pc + (r * 16 + c));
            wv[k] = *sp;
        }
        const float2 xv0 = xb[base * 16 + c];
        const float2 xv1 = xb[(base + 1) * 16 + c];
#pragma unroll
        for (int w = 0; w < WW; ++w) {
            fr[w] += xv0.x * wv[9 - w].x;
            fi[w] += xv0.y * wv[9 - w].y;
            fr[w] += xv1.x * wv[10 - w].x;
            fi[w] += xv1.y * wv[10 - w].y;
        }
    }
#undef STAGE

    // ---- reduce over tc: xor-reduce within wave, then 16 wave-partials via LDS ----
#pragma unroll
    for (int w = 0; w < WW; ++w) {
        fr[w] += __shfl_xor(fr[w], 16);
        fr[w] += __shfl_xor(fr[w], 32);
        fi[w] += __shfl_xor(fi[w], 16);
        fi[w] += __shfl_xor(fi[w], 32);
    }
    float (*red)[320] = (float (*)[320])smem;   // 20480 B overlay
    float* F2 = (float*)(smem + 20480);         // 1280 B
    float* nls = (float*)(smem + 21760);        // 1280 B
    if (lane < 16) {  // lane == c for these lanes
#pragma unroll
        for (int w = 0; w < WW; ++w) {
            red[wave][lane * 20 + w] = fr[w];
            red[wave][lane * 20 + 10 + w] = fi[w];
        }
    }
    __syncthreads();
    if (tid < 320) {
        float s = 0.f;
#pragma unroll
        for (int k = 0; k < 16; ++k) s += red[k][tid];
        F2[tid] = s;  // slot = c*20 + j*10 + w  (j=0:real, 1:imag)
    }
    __syncthreads();
    if (tid < 160) {  // amplitude scaling
        const int cc = tid / 10, w = tid % 10;
        const float a = F2[cc * 20 + w], q = F2[cc * 20 + 10 + w];
        const float amp = a * a + q * q;
        F2[cc * 20 + w] = a * amp;
        F2[cc * 20 + 10 + w] = q * amp;
    }
    __syncthreads();
    if (tid < 320) {  // nl[w,c,o] = sum_i tf[w,i] * Wnl[c,o,i]
        const int cc = tid / 20, rem = tid % 20, o = rem / 10, w = rem % 10;
        const float* __restrict__ wn = Wnl + (cc * 2 + o) * 32;
        float acc = 0.f;
#pragma unroll
        for (int i = 0; i < 16; ++i) acc += F2[i * 20 + w] * wn[i];
#pragma unroll
        for (int i = 0; i < 16; ++i) acc += F2[i * 20 + 10 + w] * wn[16 + i];
        nls[tid] = acc;  // slot = c*20 + o*10 + w
    }
    __syncthreads();
    if (tid < 32) {  // out[b,c,o] = sum_w nl[w,c,o] * Wout_o[c,w]
        const int cc = tid >> 1, o = tid & 1;
        const float* __restrict__ wo = (o == 0 ? Wor : Woi) + cc * WW;
        float acc = 0.f;
#pragma unroll
        for (int w = 0; w < WW; ++w) acc += nls[cc * 20 + o * 10 + w] * wo[w];
        outraw[b * 32 + cc * 2 + o] = acc;
    }
}

// ---------------- Fallback (no workspace): R7 register version, PK=false ----------------
__global__ __launch_bounds__(1024, 4) void fused_main_nopk(const float* __restrict__ x,
                                                           const float* __restrict__ Wr,
                                                           const float* __restrict__ Wi,
                                                           const float* __restrict__ Wnl,
                                                           const float* __restrict__ Wor,
                                                           const float* __restrict__ Woi,
                                                           float* __restrict__ outraw) {
    const int b = blockIdx.x;
    const int tid = threadIdx.x;
    const int tc = tid >> 4;
    const int c = tid & 15;
    const int n0 = tc * 64;

    const float2* __restrict__ x2 = (const float2*)x + (size_t)b * (NN * CC) + (n0 * 16 + c);

    float tr[9], ti[9];
    float fr[WW], fi[WW];
#pragma unroll
    for (int w = 0; w < WW; ++w) { fr[w] = 0.f; fi[w] = 0.f; }

#pragma unroll
    for (int j = 0; j < 9; ++j) {
        const int m = n0 - 9 + j;
        const int mc = m < 0 ? 0 : m;
        const float a = Wr[c * LL + mc], q = Wi[c * LL + mc];
        tr[j] = (m >= 0) ? a : 0.f;
        ti[j] = (m >= 0) ? q : 0.f;
    }

#pragma unroll 1
    for (int g = 0; g < 4; ++g) {
        const int nb = n0 + g * 16;
        float2 xb[16], wb[16];
#pragma unroll
        for (int p = 0; p < 16; ++p) {
            xb[p] = x2[p * 16];
            const int n = nb + p;
            const int nc2 = (n < LL) ? n : (LL - 1);
            const float a = Wr[c * LL + nc2], q = Wi[c * LL + nc2];
            wb[p].x = (n < LL) ? a : 0.f;
            wb[p].y = (n < LL) ? q : 0.f;
        }
        x2 += 256;
#pragma unroll
        for (int p = 0; p < 16; ++p) {
#pragma unroll
            for (int w = 0; w < WW; ++w) {
                const int q = p - w;
                const float wr_ = (q >= 0) ? wb[q].x : tr[q + 9];
                const float wi_ = (q >= 0) ? wb[q].y : ti[q + 9];
                fr[w] += xb[p].x * wr_;
                fi[w] += xb[p].y * wi_;
            }
        }
#pragma unroll
        for (int j = 0; j < 9; ++j) { tr[j] = wb[j + 7].x; ti[j] = wb[j + 7].y; }
    }

#pragma unroll
    for (int w = 0; w < WW; ++w) {
        fr[w] += __shfl_xor(fr[w], 16);
        fr[w] += __shfl_xor(fr[w], 32);
        fi[w] += __shfl_xor(fi[w], 16);
        fi[w] += __shfl_xor(fi[w], 32);
    }
    __shared__ float red[16][320];
    __shared__ float F2[320];
    __shared__ float nls[320];
    const int lane = tid & 63, wave = tid >> 6;
    if (lane < 16) {
#pragma unroll
        for (int w = 0; w < WW; ++w) {
            red[wave][lane * 20 + w] = fr[w];
            red[wave][lane * 20 + 10 + w] = fi[w];
        }
    }
    __syncthreads();
    if (tid < 320) {
        float s = 0.f;
#pragma unroll
        for (int k = 0; k < 16; ++k) s += red[k][tid];
        F2[tid] = s;
    }
    __syncthreads();
    if (tid < 160) {
        const int cc = tid / 10, w = tid % 10;
        const float a = F2[cc * 20 + w], q = F2[cc * 20 + 10 + w];
        const float amp = a * a + q * q;
        F2[cc * 20 + w] = a * amp;
        F2[cc * 20 + 10 + w] = q * amp;
    }
    __syncthreads();
    if (tid < 320) {
        const int cc = tid / 20, rem = tid % 20, o = rem / 10, w = rem % 10;
        const float* __restrict__ wn = Wnl + (cc * 2 + o) * 32;
        float acc = 0.f;
#pragma unroll
        for (int i = 0; i < 16; ++i) acc += F2[i * 20 + w] * wn[i];
#pragma unroll
        for (int i = 0; i < 16; ++i) acc += F2[i * 20 + 10 + w] * wn[16 + i];
        nls[tid] = acc;
    }
    __syncthreads();
    if (tid < 32) {
        const int cc = tid >> 1, o = tid & 1;
        const float* __restrict__ wo = (o == 0 ? Wor : Woi) + cc * WW;
        float acc = 0.f;
#pragma unroll
        for (int w = 0; w < WW; ++w) acc += nls[cc * 20 + o * 10 + w] * wo[w];
        outraw[b * 32 + cc * 2 + o] = acc;
    }
}

// ---------------- Kernel 2: BatchNorm in place on d_out ----------------
__global__ __launch_bounds__(256) void bnorm(float* __restrict__ out,
                                             const float* __restrict__ gamma,
                                             const float* __restrict__ beta) {
    const int c = blockIdx.x;   // [0,16)
    const int t = threadIdx.x;  // [0,256) == b
    const float v0 = out[t * 32 + c * 2 + 0];
    const float v1 = out[t * 32 + c * 2 + 1];
    float s = v0 + v1;
    float ss = v0 * v0 + v1 * v1;
#pragma unroll
    for (int off = 32; off > 0; off >>= 1) {
        s += __shfl_down(s, off, 64);
        ss += __shfl_down(ss, off, 64);
    }
    __shared__ float ls[8];
    const int wave = t >> 6, lane = t & 63;
    if (lane == 0) { ls[wave * 2] = s; ls[wave * 2 + 1] = ss; }
    __syncthreads();
    const float S = ls[0] + ls[2] + ls[4] + ls[6];
    const float SS = ls[1] + ls[3] + ls[5] + ls[7];
    const float mean = S * (1.f / 512.f);
    const float var = SS * (1.f / 512.f) - mean * mean;
    const float scale = gamma[c] * rsqrtf(var + EPSF);
    const float sh = beta[c];
    out[t * 32 + c * 2 + 0] = (v0 - mean) * scale + sh;
    out[t * 32 + c * 2 + 1] = (v1 - mean) * scale + sh;
}

extern "C" void kernel_launch(void* const* d_in, const int* in_sizes, int n_in,
                              void* d_out, int out_size, void* d_ws, size_t ws_size,
                              hipStream_t stream) {
    const float* x     = (const float*)d_in[0];
    const float* Wr    = (const float*)d_in[1];
    const float* Wi    = (const float*)d_in[2];
    const float* Wnl   = (const float*)d_in[3];
    const float* Wor   = (const float*)d_in[4];
    const float* Woi   = (const float*)d_in[5];
    const float* gamma = (const float*)d_in[6];
    const float* beta  = (const float*)d_in[7];
    float* out = (float*)d_out;

    const size_t pk_bytes = (size_t)NN * CC * sizeof(float2);  // 524288
    float2* pk = (float2*)d_ws;
    const bool use_pk = (ws_size >= pk_bytes);  // ws_size fixed -> same path every call

    if (use_pk) {
        hipLaunchKernelGGL(pack_weights, dim3(256), dim3(256), 0, stream, Wr, Wi, pk);
        hipLaunchKernelGGL(fused_pipe, dim3(BB), dim3(1024), 0, stream,
                           x, pk, Wnl, Wor, Woi, out);
    } else {
        hipLaunchKernelGGL(fused_main_nopk, dim3(BB), dim3(1024), 0, stream,
                           x, Wr, Wi, Wnl, Wor, Woi, out);
    }
    hipLaunchKernelGGL(bnorm, dim3(CC), dim3(256), 0, stream, out, gamma, beta);
}

// Round 5
// 212.391 us; speedup vs baseline: 1.0216x; 1.0216x over previous
//
#include <hip/hip_runtime.h>

#define BB 256
#define NN 4096
#define CC 16
#define WW 10
#define LL 4087  // N - W + 1
#define EPSF 1e-5f

// ---------------- Kernel 0: pack + zero-pad weights into ws (512 KB) ----------------
// pk[n*16+c] = {Wr[c,n], Wi[c,n]}, zeros for n >= LL
__global__ __launch_bounds__(256) void pack_weights(const float* __restrict__ Wr,
                                                    const float* __restrict__ Wi,
                                                    float2* __restrict__ pk) {
    int tg = blockIdx.x * 256 + threadIdx.x;  // [0, 65536)
    int n = tg >> 4, c = tg & 15;
    float2 v = make_float2(0.f, 0.f);
    if (n < LL) { v.x = Wr[c * LL + n]; v.y = Wi[c * LL + n]; }
    pk[tg] = v;
}

// ---------------- Kernel A (R10): stage-1 partials, 1024 blocks x 256 threads ----------
// HISTORY:
//  R3: float4/nt loads regressed. R5: BN fusion regressed.
//  R6 FAILED: reg batching under 64-VGPR cap -> scratch spill, 213us.
//  R7 NEUTRAL (~65us): batched reg loads, (1024,4), no spill, no barriers in loop.
//  R8 NEUTRAL (~66us): LDS staging via global_load_lds, syncthreads/tile.
//  R9 NEUTRAL (~65us): counted-vmcnt 4-buffer pipeline (T3/T4), raw s_barrier.
//  => FOUR structures pinned at ~65us = 3x the 20us x-BW floor. Spill, latency
//     depth, and DRAM pattern each excluded. Remaining shared factor: grid=256
//     blocks of 1024 on 256 CUs -- 1 block/CU, zero scheduling slack; duration =
//     slowest CU's full serial 512KiB walk (stragglers/imbalance unamortized).
//  R10: split stage1 into 1024 blocks x 256 threads (4 blocks/CU, same 16 waves/CU);
//     R7's register body verbatim; NO barriers, NO atomics; 16 per-(b,wave) partial
//     vectors to ws; epilogue in a separate tiny kernel.
__global__ __launch_bounds__(256, 4) void stage1(const float* __restrict__ x,
                                                 const float2* __restrict__ pk,
                                                 float* __restrict__ fpart) {
    const int bid = blockIdx.x;       // [0,1024)
    const int b = bid >> 2, q = bid & 3;
    const int tid = threadIdx.x;      // [0,256)
    const int tc = tid >> 4;          // 0..15
    const int c = tid & 15;
    const int n0 = q * 1024 + tc * 64;

    const float2* __restrict__ x2 = (const float2*)x + (size_t)b * (NN * CC) + (n0 * 16 + c);
    const float2* __restrict__ pkp = pk + (n0 * 16 + c);

    float tr[9], ti[9];
    float fr[WW], fi[WW];
#pragma unroll
    for (int w = 0; w < WW; ++w) { fr[w] = 0.f; fi[w] = 0.f; }

    // prefill tail with weights n0-9..n0-1 (zero if negative; pk is zero-padded above LL)
#pragma unroll
    for (int j = 0; j < 9; ++j) {
        const int m = n0 - 9 + j;
        float vr = 0.f, vi = 0.f;
        if (m >= 0) { const float2 t = pk[m * 16 + c]; vr = t.x; vi = t.y; }
        tr[j] = vr;
        ti[j] = vi;
    }

    // 4 chunks of 16 steps; batched loads; one chunk's buffers live at a time.
#pragma unroll 1
    for (int g = 0; g < 4; ++g) {
        float2 xb[16], wb[16];
#pragma unroll
        for (int p = 0; p < 16; ++p) {
            xb[p] = x2[p * 16];
            wb[p] = pkp[p * 16];
        }
        x2 += 256;
        pkp += 256;
#pragma unroll
        for (int p = 0; p < 16; ++p) {
#pragma unroll
            for (int w = 0; w < WW; ++w) {
                const int u = p - w;  // compile-time
                const float wr_ = (u >= 0) ? wb[u].x : tr[u + 9];
                const float wi_ = (u >= 0) ? wb[u].y : ti[u + 9];
                fr[w] += xb[p].x * wr_;
                fi[w] += xb[p].y * wi_;
            }
        }
#pragma unroll
        for (int j = 0; j < 9; ++j) { tr[j] = wb[j + 7].x; ti[j] = wb[j + 7].y; }
    }

    // reduce the 4 tc's within each wave (tc low bits = lane bits 4..5)
#pragma unroll
    for (int w = 0; w < WW; ++w) {
        fr[w] += __shfl_xor(fr[w], 16);
        fr[w] += __shfl_xor(fr[w], 32);
        fi[w] += __shfl_xor(fi[w], 16);
        fi[w] += __shfl_xor(fi[w], 32);
    }
    // lanes 0..15 (lane == c) write this wave's partial: row = bid*4 + wave
    const int lane = tid & 63, wave = tid >> 6;
    if (lane < 16) {
        float* __restrict__ dst = fpart + (size_t)(bid * 4 + wave) * 320 + lane * 20;
#pragma unroll
        for (int w = 0; w < WW; ++w) {
            dst[w] = fr[w];
            dst[10 + w] = fi[w];
        }
    }
}

// ---------------- Kernel B (R10): sum partials + amp + nl + out, one block per b -------
__global__ __launch_bounds__(320) void epilogue(const float* __restrict__ fpart,
                                                const float* __restrict__ Wnl,
                                                const float* __restrict__ Wor,
                                                const float* __restrict__ Woi,
                                                float* __restrict__ outraw) {
    const int b = blockIdx.x;   // [0,256)
    const int tid = threadIdx.x;  // [0,320)
    __shared__ float F2[320];
    __shared__ float nls[320];

    float s = 0.f;
    const float* __restrict__ fp = fpart + (size_t)b * 16 * 320 + tid;
#pragma unroll
    for (int k = 0; k < 16; ++k) s += fp[k * 320];
    F2[tid] = s;  // slot = c*20 + j*10 + w (j=0:real, 1:imag)
    __syncthreads();
    if (tid < 160) {  // amplitude scaling
        const int cc = tid / 10, w = tid % 10;
        const float a = F2[cc * 20 + w], qq = F2[cc * 20 + 10 + w];
        const float amp = a * a + qq * qq;
        F2[cc * 20 + w] = a * amp;
        F2[cc * 20 + 10 + w] = qq * amp;
    }
    __syncthreads();
    {  // nl[w,c,o] = sum_i tf[w,i] * Wnl[c,o,i]
        const int cc = tid / 20, rem = tid % 20, o = rem / 10, w = rem % 10;
        const float* __restrict__ wn = Wnl + (cc * 2 + o) * 32;
        float acc = 0.f;
#pragma unroll
        for (int i = 0; i < 16; ++i) acc += F2[i * 20 + w] * wn[i];
#pragma unroll
        for (int i = 0; i < 16; ++i) acc += F2[i * 20 + 10 + w] * wn[16 + i];
        nls[tid] = acc;  // slot = c*20 + o*10 + w
    }
    __syncthreads();
    if (tid < 32) {  // out[b,c,o] = sum_w nl[w,c,o] * Wout_o[c,w]
        const int cc = tid >> 1, o = tid & 1;
        const float* __restrict__ wo = (o == 0 ? Wor : Woi) + cc * WW;
        float acc = 0.f;
#pragma unroll
        for (int w = 0; w < WW; ++w) acc += nls[cc * 20 + o * 10 + w] * wo[w];
        outraw[b * 32 + cc * 2 + o] = acc;
    }
}

// ---------------- Fallback (no workspace): R7 register version, PK=false ----------------
__global__ __launch_bounds__(1024, 4) void fused_main_nopk(const float* __restrict__ x,
                                                           const float* __restrict__ Wr,
                                                           const float* __restrict__ Wi,
                                                           const float* __restrict__ Wnl,
                                                           const float* __restrict__ Wor,
                                                           const float* __restrict__ Woi,
                                                           float* __restrict__ outraw) {
    const int b = blockIdx.x;
    const int tid = threadIdx.x;
    const int tc = tid >> 4;
    const int c = tid & 15;
    const int n0 = tc * 64;

    const float2* __restrict__ x2 = (const float2*)x + (size_t)b * (NN * CC) + (n0 * 16 + c);

    float tr[9], ti[9];
    float fr[WW], fi[WW];
#pragma unroll
    for (int w = 0; w < WW; ++w) { fr[w] = 0.f; fi[w] = 0.f; }

#pragma unroll
    for (int j = 0; j < 9; ++j) {
        const int m = n0 - 9 + j;
        const int mc = m < 0 ? 0 : m;
        const float a = Wr[c * LL + mc], q = Wi[c * LL + mc];
        tr[j] = (m >= 0) ? a : 0.f;
        ti[j] = (m >= 0) ? q : 0.f;
    }

#pragma unroll 1
    for (int g = 0; g < 4; ++g) {
        const int nb = n0 + g * 16;
        float2 xb[16], wb[16];
#pragma unroll
        for (int p = 0; p < 16; ++p) {
            xb[p] = x2[p * 16];
            const int n = nb + p;
            const int nc2 = (n < LL) ? n : (LL - 1);
            const float a = Wr[c * LL + nc2], q = Wi[c * LL + nc2];
            wb[p].x = (n < LL) ? a : 0.f;
            wb[p].y = (n < LL) ? q : 0.f;
        }
        x2 += 256;
#pragma unroll
        for (int p = 0; p < 16; ++p) {
#pragma unroll
            for (int w = 0; w < WW; ++w) {
                const int u = p - w;
                const float wr_ = (u >= 0) ? wb[u].x : tr[u + 9];
                const float wi_ = (u >= 0) ? wb[u].y : ti[u + 9];
                fr[w] += xb[p].x * wr_;
                fi[w] += xb[p].y * wi_;
            }
        }
#pragma unroll
        for (int j = 0; j < 9; ++j) { tr[j] = wb[j + 7].x; ti[j] = wb[j + 7].y; }
    }

#pragma unroll
    for (int w = 0; w < WW; ++w) {
        fr[w] += __shfl_xor(fr[w], 16);
        fr[w] += __shfl_xor(fr[w], 32);
        fi[w] += __shfl_xor(fi[w], 16);
        fi[w] += __shfl_xor(fi[w], 32);
    }
    __shared__ float red[16][320];
    __shared__ float F2[320];
    __shared__ float nls[320];
    const int lane = tid & 63, wave = tid >> 6;
    if (lane < 16) {
#pragma unroll
        for (int w = 0; w < WW; ++w) {
            red[wave][lane * 20 + w] = fr[w];
            red[wave][lane * 20 + 10 + w] = fi[w];
        }
    }
    __syncthreads();
    if (tid < 320) {
        float s = 0.f;
#pragma unroll
        for (int k = 0; k < 16; ++k) s += red[k][tid];
        F2[tid] = s;
    }
    __syncthreads();
    if (tid < 160) {
        const int cc = tid / 10, w = tid % 10;
        const float a = F2[cc * 20 + w], q = F2[cc * 20 + 10 + w];
        const float amp = a * a + q * q;
        F2[cc * 20 + w] = a * amp;
        F2[cc * 20 + 10 + w] = q * amp;
    }
    __syncthreads();
    if (tid < 320) {
        const int cc = tid / 20, rem = tid % 20, o = rem / 10, w = rem % 10;
        const float* __restrict__ wn = Wnl + (cc * 2 + o) * 32;
        float acc = 0.f;
#pragma unroll
        for (int i = 0; i < 16; ++i) acc += F2[i * 20 + w] * wn[i];
#pragma unroll
        for (int i = 0; i < 16; ++i) acc += F2[i * 20 + 10 + w] * wn[16 + i];
        nls[tid] = acc;
    }
    __syncthreads();
    if (tid < 32) {
        const int cc = tid >> 1, o = tid & 1;
        const float* __restrict__ wo = (o == 0 ? Wor : Woi) + cc * WW;
        float acc = 0.f;
#pragma unroll
        for (int w = 0; w < WW; ++w) acc += nls[cc * 20 + o * 10 + w] * wo[w];
        outraw[b * 32 + cc * 2 + o] = acc;
    }
}

// ---------------- Kernel 2: BatchNorm in place on d_out ----------------
__global__ __launch_bounds__(256) void bnorm(float* __restrict__ out,
                                             const float* __restrict__ gamma,
                                             const float* __restrict__ beta) {
    const int c = blockIdx.x;   // [0,16)
    const int t = threadIdx.x;  // [0,256) == b
    const float v0 = out[t * 32 + c * 2 + 0];
    const float v1 = out[t * 32 + c * 2 + 1];
    float s = v0 + v1;
    float ss = v0 * v0 + v1 * v1;
#pragma unroll
    for (int off = 32; off > 0; off >>= 1) {
        s += __shfl_down(s, off, 64);
        ss += __shfl_down(ss, off, 64);
    }
    __shared__ float ls[8];
    const int wave = t >> 6, lane = t & 63;
    if (lane == 0) { ls[wave * 2] = s; ls[wave * 2 + 1] = ss; }
    __syncthreads();
    const float S = ls[0] + ls[2] + ls[4] + ls[6];
    const float SS = ls[1] + ls[3] + ls[5] + ls[7];
    const float mean = S * (1.f / 512.f);
    const float var = SS * (1.f / 512.f) - mean * mean;
    const float scale = gamma[c] * rsqrtf(var + EPSF);
    const float sh = beta[c];
    out[t * 32 + c * 2 + 0] = (v0 - mean) * scale + sh;
    out[t * 32 + c * 2 + 1] = (v1 - mean) * scale + sh;
}

extern "C" void kernel_launch(void* const* d_in, const int* in_sizes, int n_in,
                              void* d_out, int out_size, void* d_ws, size_t ws_size,
                              hipStream_t stream) {
    const float* x     = (const float*)d_in[0];
    const float* Wr    = (const float*)d_in[1];
    const float* Wi    = (const float*)d_in[2];
    const float* Wnl   = (const float*)d_in[3];
    const float* Wor   = (const float*)d_in[4];
    const float* Woi   = (const float*)d_in[5];
    const float* gamma = (const float*)d_in[6];
    const float* beta  = (const float*)d_in[7];
    float* out = (float*)d_out;

    const size_t pk_bytes = (size_t)NN * CC * sizeof(float2);            // 524288
    const size_t fp_bytes = (size_t)4096 * 320 * sizeof(float);          // 5242880
    float2* pk = (float2*)d_ws;
    float* fpart = (float*)((char*)d_ws + pk_bytes);
    const bool use_ws = (ws_size >= pk_bytes + fp_bytes);  // fixed -> same path each call

    if (use_ws) {
        hipLaunchKernelGGL(pack_weights, dim3(256), dim3(256), 0, stream, Wr, Wi, pk);
        hipLaunchKernelGGL(stage1, dim3(1024), dim3(256), 0, stream, x, pk, fpart);
        hipLaunchKernelGGL(epilogue, dim3(BB), dim3(320), 0, stream,
                           fpart, Wnl, Wor, Woi, out);
    } else {
        hipLaunchKernelGGL(fused_main_nopk, dim3(BB), dim3(1024), 0, stream,
                           x, Wr, Wi, Wnl, Wor, Woi, out);
    }
    hipLaunchKernelGGL(bnorm, dim3(CC), dim3(256), 0, stream, out, gamma, beta);
}